// Round 20
// baseline (260.093 us; speedup 1.0000x reference)
//
#include <hip/hip_runtime.h>
#include <hip/hip_bf16.h>

#define NN 50000
#define NE 800000
#define NBKT 196          // bucket = dst >> 8 (256 nodes per bucket)
#define EPB 2048          // edges per histogram/sort block
#define NCB 391           // ceil(NE / EPB)
#define AGG_GRID 2048     // persistent agg blocks (grid-stride over node groups)

// prep kernel block ranges
#define PB_BH   NCB
#define PB_PW1  (PB_BH + 32)
#define PB_PW2  (PB_PW1 + 16)
#define PB_PA1  (PB_PW2 + 2)
#define PB_PA2  (PB_PA1 + 1)

// passD block ranges (bucket node-sort ∥ layer-1 GEMM, 1024-thread blocks)
#define DB_BKT  NBKT
#define DB_GT   782            // ceil(3125 gemm tiles / 4)
#define DB_ALL  (DB_BKT + DB_GT)

typedef __attribute__((ext_vector_type(8))) short bf16x8;
typedef __attribute__((ext_vector_type(4))) float f32x4;

__device__ __forceinline__ float2 bfp(uint32_t u) {
    union { uint32_t i; float f; } lo, hi;
    lo.i = u << 16;
    hi.i = u & 0xffff0000u;
    return make_float2(lo.f, hi.f);
}
__device__ __forceinline__ float bf1(uint16_t u) {
    union { uint32_t i; float f; } x; x.i = ((uint32_t)u) << 16; return x.f;
}
__device__ __forceinline__ float4 bfp4(uint32_t a, uint32_t b) {
    const float2 lo = bfp(a), hi = bfp(b);
    return make_float4(lo.x, lo.y, hi.x, hi.y);
}

// ---------------------------------------------------------------------------
// prep: per-block bucket histogram + weight packing
// ---------------------------------------------------------------------------
template<int M>
__device__ __forceinline__ void pack_w_dev(
    int t, const float* __restrict__ Wq, const float* __restrict__ Wk,
    const float* __restrict__ Wv, const float* __restrict__ Wsk,
    const float* __restrict__ bq, const float* __restrict__ bk,
    const float* __restrict__ bv, const float* __restrict__ bsk,
    __hip_bfloat16* __restrict__ Wp, float* __restrict__ bcat)
{
    constexpr int NFQ = M / 16;
    constexpr int NF_TOT = 4 * NFQ;
    if (t >= 4 * NF_TOT * 64) return;
    const int l  = t & 63;
    const int fg = (t >> 6) % NF_TOT;
    const int s  = t / (64 * NF_TOT);
    const int sec = fg / NFQ;
    const int fl  = fg % NFQ;
    const float* W = sec == 0 ? Wq : sec == 1 ? Wk : sec == 2 ? Wv : Wsk;
    const int col = fl * 16 + (l & 15);
    const int k0  = s * 32 + (l >> 4) * 8;
    __hip_bfloat16 tmp[8];
    #pragma unroll
    for (int j = 0; j < 8; ++j) tmp[j] = __float2bfloat16(W[(size_t)(k0 + j) * M + col]);
    *reinterpret_cast<uint4*>(Wp + ((size_t)(fg * 4 + s) * 64 + l) * 8) =
        *reinterpret_cast<const uint4*>(tmp);
    if (s == 0 && (l >> 4) == 0) {
        const float* B = sec == 0 ? bq : sec == 1 ? bk : sec == 2 ? bv : bsk;
        bcat[fg * 16 + (l & 15)] = B[col];
    }
}

template<int MW, int MO>
__device__ __forceinline__ void pack_wq_dev(
    int t, const float* __restrict__ Wq, const float* __restrict__ We,
    const float* __restrict__ bq,
    __hip_bfloat16* __restrict__ Ap, float* __restrict__ B0)
{
    constexpr int NF = MO / 16;
    if (t >= 4 * NF * 64) return;
    const int l  = t & 63;
    const int fg = (t >> 6) % NF;
    const int s  = t / (64 * NF);
    const int col = fg * 16 + (l & 15);
    const int h = col >> 4;
    const int r = col & 15;
    const int k0 = s * 32 + (l >> 4) * 8;
    __hip_bfloat16 tmp[8];
    #pragma unroll
    for (int jj = 0; jj < 8; ++jj) {
        float acc = 0.f;
        for (int c = 0; c < 64; ++c)
            acc += Wq[(size_t)(k0 + jj) * MW + h * 64 + c] * We[r * MW + h * 64 + c];
        tmp[jj] = __float2bfloat16(acc * 0.125f);
    }
    *reinterpret_cast<uint4*>(Ap + ((size_t)(fg * 4 + s) * 64 + l) * 8) =
        *reinterpret_cast<const uint4*>(tmp);
    if (s == 0 && (l >> 4) == 0) {
        float acc = 0.f;
        for (int c = 0; c < 64; ++c) acc += bq[h * 64 + c] * We[r * MW + h * 64 + c];
        B0[col] = acc * 0.125f;
    }
}

__global__ __launch_bounds__(256)
void prep(const int* __restrict__ dstp, int* __restrict__ blkcnt,
          const float* Wq1, const float* Wk1, const float* Wv1, const float* Ws1,
          const float* bq1, const float* bk1, const float* bv1, const float* bs1,
          const float* We1,
          const float* Wq2, const float* Wk2, const float* Wv2, const float* Ws2,
          const float* bq2, const float* bk2, const float* bv2, const float* bs2,
          const float* We2,
          __hip_bfloat16* Wp1, float* bcat1,
          __hip_bfloat16* Wp2, float* bcat2)
{
    const int b = blockIdx.x;
    const int t = threadIdx.x;
    if (b < PB_BH) {
        __shared__ int bins[NBKT];
        if (t < NBKT) bins[t] = 0;
        __syncthreads();
        const int e0 = b * EPB;
        const int nedge = min(EPB, NE - e0);
        for (int j = 0; j < EPB / 256; ++j) {
            const int idx = t + j * 256;
            if (idx < nedge) atomicAdd(&bins[dstp[e0 + idx] >> 8], 1);
        }
        __syncthreads();
        if (t < NBKT) blkcnt[b * NBKT + t] = bins[t];
    } else if (b < PB_PW1) {
        pack_w_dev<128>((b - PB_BH) * 256 + t, Wq1, Wk1, Wv1, Ws1,
                        bq1, bk1, bv1, bs1, Wp1, bcat1);
    } else if (b < PB_PW2) {
        pack_w_dev<64>((b - PB_PW1) * 256 + t, Wq2, Wk2, Wv2, Ws2,
                       bq2, bk2, bv2, bs2, Wp2, bcat2);
    } else if (b < PB_PA1) {
        pack_wq_dev<128, 32>((b - PB_PW2) * 256 + t, Wq1, We1, bq1,
                             Wp1 + (size_t)32 * 2048, bcat1 + 512);
    } else {
        pack_wq_dev<64, 16>((b - PB_PA1) * 256 + t, Wq2, We2, bq2,
                            Wp2 + (size_t)16 * 2048, bcat2 + 256);
    }
}

// ---------------------------------------------------------------------------
// passC (1024 threads, EPB=2048): LDS-staged bucket sort carrying sidx + bf16
// ea. Sequential reads; burst write-out -> full-line writes.
// ---------------------------------------------------------------------------
__global__ __launch_bounds__(1024)
void passC(const int* __restrict__ dstp, const int* __restrict__ srcp,
           const float* __restrict__ ea, const int* __restrict__ blkcnt,
           uint32_t* __restrict__ sidx, __hip_bfloat16* __restrict__ eap1,
           int* __restrict__ bucket_start)
{
    __shared__ int gbase[NBKT];
    __shared__ int lofs0[NBKT];
    __shared__ int lcur[NBKT];
    __shared__ int stmp[256];
    __shared__ uint32_t sbuf[EPB];
    __shared__ uint4 eb0[EPB];
    __shared__ uint4 eb1[EPB];

    const int blk = blockIdx.x;
    const int t = threadIdx.x;

    int partial = 0, total = 0;
    if (t < NBKT) {
        for (int b = 0; b < NCB; ++b) {
            const int v = blkcnt[b * NBKT + t];
            partial += (b < blk) ? v : 0;
            total += v;
        }
    }
    if (t < 256) stmp[t] = (t < NBKT) ? total : 0;
    __syncthreads();
    for (int d = 1; d < 256; d <<= 1) {
        const int v = (t < 256 && t >= d) ? stmp[t - d] : 0;
        __syncthreads();
        if (t < 256) stmp[t] += v;
        __syncthreads();
    }
    if (t < NBKT) {
        const int bstart = stmp[t] - total;
        gbase[t] = bstart + partial;
        if (blk == 0) {
            bucket_start[t] = bstart;
            if (t == NBKT - 1) bucket_start[NBKT] = stmp[t];
        }
    }

    if (t < NBKT) lcur[t] = 0;
    __syncthreads();
    const int e0 = blk * EPB;
    const int nedge = min(EPB, NE - e0);
    for (int j = 0; j < EPB / 1024; ++j) {
        const int idx = t + j * 1024;
        if (idx < nedge) atomicAdd(&lcur[dstp[e0 + idx] >> 8], 1);
    }
    __syncthreads();
    if (t < 256) stmp[t] = (t < NBKT) ? lcur[t] : 0;
    __syncthreads();
    int own = 0;
    if (t < 256) own = stmp[t];
    for (int d = 1; d < 256; d <<= 1) {
        const int v = (t < 256 && t >= d) ? stmp[t - d] : 0;
        __syncthreads();
        if (t < 256) stmp[t] += v;
        __syncthreads();
    }
    if (t < NBKT) { lofs0[t] = stmp[t] - own; lcur[t] = stmp[t] - own; }
    __syncthreads();

    for (int j = 0; j < EPB / 1024; ++j) {
        const int idx = t + j * 1024;
        if (idx < nedge) {
            const int e = e0 + idx;
            const int d_ = dstp[e];
            const int bkt = d_ >> 8;
            const int q = atomicAdd(&lcur[bkt], 1);
            sbuf[q] = (uint32_t)srcp[e] | ((uint32_t)(d_ & 255) << 16)
                      | ((uint32_t)bkt << 24);
            const float4* ea4 = reinterpret_cast<const float4*>(ea) + (size_t)e * 4;
            const float4 a0 = ea4[0], a1 = ea4[1], a2 = ea4[2], a3 = ea4[3];
            const float af[16] = {a0.x,a0.y,a0.z,a0.w, a1.x,a1.y,a1.z,a1.w,
                                  a2.x,a2.y,a2.z,a2.w, a3.x,a3.y,a3.z,a3.w};
            __hip_bfloat16 tmp[16];
            #pragma unroll
            for (int r = 0; r < 16; ++r) tmp[r] = __float2bfloat16(af[r]);
            eb0[q] = *reinterpret_cast<const uint4*>(&tmp[0]);
            eb1[q] = *reinterpret_cast<const uint4*>(&tmp[8]);
        }
    }
    __syncthreads();

    for (int j = 0; j < EPB / 1024; ++j) {
        const int q = t + j * 1024;
        if (q < nedge) {
            const uint32_t v = sbuf[q];
            const int bkt = v >> 24;
            const int gpos = gbase[bkt] + (q - lofs0[bkt]);
            sidx[gpos] = v & 0x00ffffffu;
            uint4* dp = reinterpret_cast<uint4*>(eap1 + (size_t)gpos * 16);
            dp[0] = eb0[q];
            dp[1] = eb1[q];
        }
    }
}

// ---------------------------------------------------------------------------
// Fused MFMA node GEMM (device body, 256-thread granule).
// ---------------------------------------------------------------------------
template<int M, int MO, bool F32IN>
__device__ __forceinline__
void gemm_dev(int blk, int tid, const void* __restrict__ xin,
              const __hip_bfloat16* __restrict__ Wp,
              const float* __restrict__ bcat,
              __hip_bfloat16* __restrict__ q, __hip_bfloat16* __restrict__ kv,
              __hip_bfloat16* __restrict__ skip, float* __restrict__ wqo)
{
    constexpr int NF_TOT = (4 * M + MO) / 16;
    constexpr int NFW = (NF_TOT + 3) / 4;
    const int wid  = tid >> 6;
    const int l    = tid & 63;
    const int row0 = blk * 16;
    const int rowg = row0 + (l & 15);
    const int kb   = l >> 4;

    f32x4 acc[NFW];
    #pragma unroll
    for (int f = 0; f < NFW; ++f) acc[f] = f32x4{0.f, 0.f, 0.f, 0.f};

    const bf16x8* wp8 = reinterpret_cast<const bf16x8*>(Wp);
    #pragma unroll
    for (int s = 0; s < 4; ++s) {
        bf16x8 a;
        if constexpr (F32IN) {
            const float* xf = (const float*)xin;
            const float4 a0 = *reinterpret_cast<const float4*>(
                xf + (size_t)rowg * 128 + s * 32 + kb * 8);
            const float4 a1 = *reinterpret_cast<const float4*>(
                xf + (size_t)rowg * 128 + s * 32 + kb * 8 + 4);
            union { __hip_bfloat16 h[8]; bf16x8 v; } u;
            u.h[0] = __float2bfloat16(a0.x); u.h[1] = __float2bfloat16(a0.y);
            u.h[2] = __float2bfloat16(a0.z); u.h[3] = __float2bfloat16(a0.w);
            u.h[4] = __float2bfloat16(a1.x); u.h[5] = __float2bfloat16(a1.y);
            u.h[6] = __float2bfloat16(a1.z); u.h[7] = __float2bfloat16(a1.w);
            a = u.v;
        } else {
            const __hip_bfloat16* xb = (const __hip_bfloat16*)xin;
            a = *reinterpret_cast<const bf16x8*>(xb + (size_t)rowg * 128 + s * 32 + kb * 8);
        }
        #pragma unroll
        for (int f = 0; f < NFW; ++f) {
            const int fg = wid + 4 * f;
            if (fg < NF_TOT)
                acc[f] = __builtin_amdgcn_mfma_f32_16x16x32_bf16(
                    a, wp8[(size_t)(fg * 4 + s) * 64 + l], acc[f], 0, 0, 0);
        }
    }

    const int cl = l & 15;
    #pragma unroll
    for (int f = 0; f < NFW; ++f) {
        const int fg = wid + 4 * f;
        if (fg >= NF_TOT) continue;
        const int cg = fg * 16 + cl;
        const float bb = bcat[cg];
        #pragma unroll
        for (int j = 0; j < 4; ++j) {
            const int row = row0 + kb * 4 + j;
            const float val = acc[f][j] + bb;
            if (cg < M) {
                q[(size_t)row * M + cg] = __float2bfloat16(val * 0.125f);
            } else if (cg < 2 * M) {
                const int c = cg - M;
                kv[(size_t)row * 2 * M + (c >> 2) * 8 + (c & 3)] = __float2bfloat16(val);
            } else if (cg < 3 * M) {
                const int c = cg - 2 * M;
                kv[(size_t)row * 2 * M + (c >> 2) * 8 + 4 + (c & 3)] = __float2bfloat16(val);
            } else if (cg < 4 * M) {
                skip[(size_t)row * M + (cg - 3 * M)] = __float2bfloat16(val);
            } else {
                wqo[(size_t)row * MO + (cg - 4 * M)] = val;
            }
        }
    }
}

template<int M, int MO, bool F32IN>
__global__ __launch_bounds__(256)
void gemm_fused(const void* __restrict__ xin,
                const __hip_bfloat16* __restrict__ Wp,
                const float* __restrict__ bcat,
                __hip_bfloat16* __restrict__ q, __hip_bfloat16* __restrict__ kv,
                __hip_bfloat16* __restrict__ skip, float* __restrict__ wqo)
{
    gemm_dev<M, MO, F32IN>(blockIdx.x, threadIdx.x, xin, Wp, bcat, q, kv, skip, wqo);
}

// ---------------------------------------------------------------------------
// passD ∥ gemm1 (1024-thread blocks). Bucket blocks: node-level counting sort;
// writes srcs[p] and permutes eap1 -> eap. Gemm blocks: 4 GEMM tiles each.
// ---------------------------------------------------------------------------
__global__ __launch_bounds__(1024)
void passD_mid(const uint32_t* __restrict__ sidx, const __hip_bfloat16* __restrict__ eap1,
               const int* __restrict__ bucket_start,
               int* __restrict__ off, int* __restrict__ srcs,
               __hip_bfloat16* __restrict__ eap,
               const float* __restrict__ x, const __hip_bfloat16* __restrict__ Wp1,
               const float* __restrict__ bcat1, __hip_bfloat16* __restrict__ q1b,
               __hip_bfloat16* __restrict__ kv1, __hip_bfloat16* __restrict__ sk1b,
               float* __restrict__ wq1)
{
    __shared__ int nbins[256];
    __shared__ int ncur[256];
    __shared__ int stmp[256];

    if (blockIdx.x >= DB_BKT) {
        const int tile = (blockIdx.x - DB_BKT) * 4 + (threadIdx.x >> 8);
        if (tile < 3125)
            gemm_dev<128, 32, true>(tile, threadIdx.x & 255, x, Wp1, bcat1,
                                    q1b, kv1, sk1b, wq1);
        return;
    }

    const int b = blockIdx.x;
    const int t = threadIdx.x;
    const int bs = bucket_start[b];
    const int be = bucket_start[b + 1];

    if (t < 256) nbins[t] = 0;
    __syncthreads();
    for (int i = bs + t; i < be; i += 1024)
        atomicAdd(&nbins[(sidx[i] >> 16) & 255], 1);
    __syncthreads();

    if (t < 256) stmp[t] = nbins[t];
    __syncthreads();
    for (int d = 1; d < 256; d <<= 1) {
        const int v = (t < 256 && t >= d) ? stmp[t - d] : 0;
        __syncthreads();
        if (t < 256) stmp[t] += v;
        __syncthreads();
    }
    if (t < 256) {
        const int own = nbins[t];
        const int excl = stmp[t] - own;
        ncur[t] = excl;
        const int node = b * 256 + t;
        if (node <= NN) off[node] = bs + excl;
    }
    __syncthreads();

    for (int i = bs + t; i < be; i += 1024) {
        const uint32_t v = sidx[i];
        const int dl = (v >> 16) & 255;
        const int p = bs + atomicAdd(&ncur[dl], 1);
        srcs[p] = (int)(v & 0xffffu);
        const uint4* sp = reinterpret_cast<const uint4*>(eap1 + (size_t)i * 16);
        uint4* dp = reinterpret_cast<uint4*>(eap + (size_t)p * 16);
        dp[0] = sp[0];
        dp[1] = sp[1];
    }
}

// ---------------------------------------------------------------------------
// Layer-1 aggregation, PERSISTENT blocks: grid-stride over 4-node groups,
// We staged in LDS once per block. Lane owns 4 channels; interleaved kv ->
// one uint4 gather per edge per lane; 2 edges/pass x4 unrolled.
// ---------------------------------------------------------------------------
__global__ __launch_bounds__(256)
void agg_l1(const int* __restrict__ off, const int* __restrict__ srcs,
            const __hip_bfloat16* __restrict__ eap,
            const float* __restrict__ We,              // [16,128]
            const float* __restrict__ wq,              // [N,32]
            const __hip_bfloat16* __restrict__ qb,     // [N,128] bf16, pre-scaled
            const __hip_bfloat16* __restrict__ kv,     // [N,256] interleaved k|v
            const __hip_bfloat16* __restrict__ skb,    // [N,128] bf16
            __hip_bfloat16* __restrict__ hb)
{
    __shared__ float wes[16 * 128];
    for (int i = threadIdx.x; i < 16 * 128; i += 256) wes[i] = We[i];
    __syncthreads();

    const int lane = threadIdx.x & 63;
    const int wv_  = threadIdx.x >> 6;
    const int hf   = lane >> 5;
    const int hl   = lane & 31;
    const int g    = lane & 15;
    const int ch   = hl * 4;
    const uint16_t* qu  = reinterpret_cast<const uint16_t*>(qb);
    const uint16_t* kvu = reinterpret_cast<const uint16_t*>(kv);
    const uint16_t* eau = reinterpret_cast<const uint16_t*>(eap);
    const uint16_t* sku = reinterpret_cast<const uint16_t*>(skb);
    const int gb = lane & 16;

    for (int grp = blockIdx.x; grp < NN / 4; grp += AGG_GRID) {
        const int node = grp * 4 + wv_;
        const size_t nb = (size_t)node * 128;
        const uint2 qw = *reinterpret_cast<const uint2*>(qu + nb + ch);
        const float4 qv = bfp4(qw.x, qw.y);
        const float wqv = wq[(size_t)node * 32 + (hl >> 4) * 16 + g];

        float acc0 = 0.f, acc1 = 0.f, acc2 = 0.f, acc3 = 0.f, den = 0.f, eacc = 0.f;
        const int beg = off[node], end = off[node + 1];

        for (int i = beg; i < end; i += 8) {
            const int ii0 = i + hf,     ii1 = i + 2 + hf;
            const int ii2 = i + 4 + hf, ii3 = i + 6 + hf;
            const bool v0 = ii0 < end, v1 = ii1 < end, v2 = ii2 < end, v3 = ii3 < end;
            const int i0 = v0 ? ii0 : beg, i1 = v1 ? ii1 : beg;
            const int i2 = v2 ? ii2 : beg, i3 = v3 ? ii3 : beg;
            const int s0 = srcs[i0], s1 = srcs[i1], s2 = srcs[i2], s3 = srcs[i3];
            const uint4 x0 = *reinterpret_cast<const uint4*>(kvu + (size_t)s0 * 256 + hl * 8);
            const uint4 x1 = *reinterpret_cast<const uint4*>(kvu + (size_t)s1 * 256 + hl * 8);
            const uint4 x2 = *reinterpret_cast<const uint4*>(kvu + (size_t)s2 * 256 + hl * 8);
            const uint4 x3 = *reinterpret_cast<const uint4*>(kvu + (size_t)s3 * 256 + hl * 8);
            const float ea0 = bf1(eau[(size_t)i0 * 16 + g]);
            const float ea1 = bf1(eau[(size_t)i1 * 16 + g]);
            const float ea2 = bf1(eau[(size_t)i2 * 16 + g]);
            const float ea3 = bf1(eau[(size_t)i3 * 16 + g]);
            const float4 k0 = bfp4(x0.x, x0.y), k1 = bfp4(x1.x, x1.y);
            const float4 k2 = bfp4(x2.x, x2.y), k3 = bfp4(x3.x, x3.y);
            float p0 = fmaf(qv.x, k0.x, fmaf(qv.y, k0.y,
                       fmaf(qv.z, k0.z, fmaf(qv.w, k0.w, ea0 * wqv))));
            float p1 = fmaf(qv.x, k1.x, fmaf(qv.y, k1.y,
                       fmaf(qv.z, k1.z, fmaf(qv.w, k1.w, ea1 * wqv))));
            float p2 = fmaf(qv.x, k2.x, fmaf(qv.y, k2.y,
                       fmaf(qv.z, k2.z, fmaf(qv.w, k2.w, ea2 * wqv))));
            float p3 = fmaf(qv.x, k3.x, fmaf(qv.y, k3.y,
                       fmaf(qv.z, k3.z, fmaf(qv.w, k3.w, ea3 * wqv))));
            #pragma unroll
            for (int m = 1; m < 16; m <<= 1) {
                p0 += __shfl_xor(p0, m, 64);
                p1 += __shfl_xor(p1, m, 64);
                p2 += __shfl_xor(p2, m, 64);
                p3 += __shfl_xor(p3, m, 64);
            }
            const float ex0 = v0 ? __expf(p0) : 0.f;
            const float ex1 = v1 ? __expf(p1) : 0.f;
            const float ex2 = v2 ? __expf(p2) : 0.f;
            const float ex3 = v3 ? __expf(p3) : 0.f;
            const float4 w0 = bfp4(x0.z, x0.w), w1 = bfp4(x1.z, x1.w);
            const float4 w2 = bfp4(x2.z, x2.w), w3 = bfp4(x3.z, x3.w);
            acc0 = fmaf(ex0, w0.x, fmaf(ex1, w1.x, fmaf(ex2, w2.x, fmaf(ex3, w3.x, acc0))));
            acc1 = fmaf(ex0, w0.y, fmaf(ex1, w1.y, fmaf(ex2, w2.y, fmaf(ex3, w3.y, acc1))));
            acc2 = fmaf(ex0, w0.z, fmaf(ex1, w1.z, fmaf(ex2, w2.z, fmaf(ex3, w3.z, acc2))));
            acc3 = fmaf(ex0, w0.w, fmaf(ex1, w1.w, fmaf(ex2, w2.w, fmaf(ex3, w3.w, acc3))));
            den += (ex0 + ex1) + (ex2 + ex3);
            eacc = fmaf(ex0, ea0, fmaf(ex1, ea1, fmaf(ex2, ea2, fmaf(ex3, ea3, eacc))));
        }

        acc0 += __shfl_xor(acc0, 32, 64);
        acc1 += __shfl_xor(acc1, 32, 64);
        acc2 += __shfl_xor(acc2, 32, 64);
        acc3 += __shfl_xor(acc3, 32, 64);
        den  += __shfl_xor(den, 32, 64);
        eacc += __shfl_xor(eacc, 32, 64);

        #pragma unroll
        for (int r = 0; r < 16; ++r) {
            const float er = __shfl(eacc, gb + r, 64);
            const float4 w = *reinterpret_cast<const float4*>(&wes[r * 128 + ch]);
            acc0 = fmaf(er, w.x, acc0);
            acc1 = fmaf(er, w.y, acc1);
            acc2 = fmaf(er, w.z, acc2);
            acc3 = fmaf(er, w.w, acc3);
        }

        if (hf == 0) {
            const float inv = 1.f / (den + 1e-16f);
            const uint2 skw = *reinterpret_cast<const uint2*>(sku + nb + ch);
            const float4 sk = bfp4(skw.x, skw.y);
            __hip_bfloat16 hp[4] = {
                __float2bfloat16(fmaxf(fmaf(acc0, inv, sk.x), 0.f)),
                __float2bfloat16(fmaxf(fmaf(acc1, inv, sk.y), 0.f)),
                __float2bfloat16(fmaxf(fmaf(acc2, inv, sk.z), 0.f)),
                __float2bfloat16(fmaxf(fmaf(acc3, inv, sk.w), 0.f))};
            *reinterpret_cast<uint2*>(hb + nb + ch) = *reinterpret_cast<const uint2*>(hp);
        }
    }
}

// ---------------------------------------------------------------------------
// Layer-2 aggregation, PERSISTENT blocks: grid-stride over 4-node groups.
// Lane owns 4 channels; 4 edges/pass (16 lanes each) x2 unrolled. Out f32.
// ---------------------------------------------------------------------------
__global__ __launch_bounds__(256)
void agg_l2(const int* __restrict__ off, const int* __restrict__ srcs,
            const __hip_bfloat16* __restrict__ eap,
            const float* __restrict__ We,              // [16,64]
            const float* __restrict__ wq,              // [N,16]
            const __hip_bfloat16* __restrict__ qb,     // [N,64] bf16, pre-scaled
            const __hip_bfloat16* __restrict__ kv,     // [N,128] interleaved k|v
            const __hip_bfloat16* __restrict__ skb,    // [N,64] bf16
            float* __restrict__ out)
{
    __shared__ float wes[16 * 64];
    for (int i = threadIdx.x; i < 16 * 64; i += 256) wes[i] = We[i];
    __syncthreads();

    const int lane = threadIdx.x & 63;
    const int wv_  = threadIdx.x >> 6;
    const int grpL = lane >> 4;
    const int g    = lane & 15;
    const int ch   = g * 4;
    const uint16_t* qu  = reinterpret_cast<const uint16_t*>(qb);
    const uint16_t* kvu = reinterpret_cast<const uint16_t*>(kv);
    const uint16_t* eau = reinterpret_cast<const uint16_t*>(eap);
    const uint16_t* sku = reinterpret_cast<const uint16_t*>(skb);

    for (int grp = blockIdx.x; grp < NN / 4; grp += AGG_GRID) {
        const int node = grp * 4 + wv_;
        const size_t nb = (size_t)node * 64;
        const uint2 qw = *reinterpret_cast<const uint2*>(qu + nb + ch);
        const float4 qv = bfp4(qw.x, qw.y);
        const float wqv = wq[(size_t)node * 16 + g];

        float acc0 = 0.f, acc1 = 0.f, acc2 = 0.f, acc3 = 0.f, den = 0.f, eacc = 0.f;
        const int beg = off[node], end = off[node + 1];

        for (int i = beg; i < end; i += 8) {
            const int ii0 = i + grpL, ii1 = i + 4 + grpL;
            const bool v0 = ii0 < end, v1 = ii1 < end;
            const int i0 = v0 ? ii0 : beg, i1 = v1 ? ii1 : beg;
            const int s0 = srcs[i0], s1 = srcs[i1];
            const uint4 x0 = *reinterpret_cast<const uint4*>(kvu + (size_t)s0 * 128 + g * 8);
            const uint4 x1 = *reinterpret_cast<const uint4*>(kvu + (size_t)s1 * 128 + g * 8);
            const float ea0 = bf1(eau[(size_t)i0 * 16 + g]);
            const float ea1 = bf1(eau[(size_t)i1 * 16 + g]);
            const float4 k0 = bfp4(x0.x, x0.y), k1 = bfp4(x1.x, x1.y);
            float p0 = fmaf(qv.x, k0.x, fmaf(qv.y, k0.y,
                       fmaf(qv.z, k0.z, fmaf(qv.w, k0.w, ea0 * wqv))));
            float p1 = fmaf(qv.x, k1.x, fmaf(qv.y, k1.y,
                       fmaf(qv.z, k1.z, fmaf(qv.w, k1.w, ea1 * wqv))));
            #pragma unroll
            for (int m = 1; m < 16; m <<= 1) {
                p0 += __shfl_xor(p0, m, 64);
                p1 += __shfl_xor(p1, m, 64);
            }
            const float ex0 = v0 ? __expf(p0) : 0.f;
            const float ex1 = v1 ? __expf(p1) : 0.f;
            const float4 w0 = bfp4(x0.z, x0.w), w1 = bfp4(x1.z, x1.w);
            acc0 = fmaf(ex0, w0.x, fmaf(ex1, w1.x, acc0));
            acc1 = fmaf(ex0, w0.y, fmaf(ex1, w1.y, acc1));
            acc2 = fmaf(ex0, w0.z, fmaf(ex1, w1.z, acc2));
            acc3 = fmaf(ex0, w0.w, fmaf(ex1, w1.w, acc3));
            den += ex0 + ex1;
            eacc = fmaf(ex0, ea0, fmaf(ex1, ea1, eacc));
        }

        acc0 += __shfl_xor(acc0, 16, 64);  acc0 += __shfl_xor(acc0, 32, 64);
        acc1 += __shfl_xor(acc1, 16, 64);  acc1 += __shfl_xor(acc1, 32, 64);
        acc2 += __shfl_xor(acc2, 16, 64);  acc2 += __shfl_xor(acc2, 32, 64);
        acc3 += __shfl_xor(acc3, 16, 64);  acc3 += __shfl_xor(acc3, 32, 64);
        den  += __shfl_xor(den, 16, 64);   den  += __shfl_xor(den, 32, 64);
        eacc += __shfl_xor(eacc, 16, 64);  eacc += __shfl_xor(eacc, 32, 64);

        #pragma unroll
        for (int r = 0; r < 16; ++r) {
            const float er = __shfl(eacc, r, 64);
            const float4 w = *reinterpret_cast<const float4*>(&wes[r * 64 + ch]);
            acc0 = fmaf(er, w.x, acc0);
            acc1 = fmaf(er, w.y, acc1);
            acc2 = fmaf(er, w.z, acc2);
            acc3 = fmaf(er, w.w, acc3);
        }

        if (lane < 16) {
            const float inv = 1.f / (den + 1e-16f);
            const uint2 skw = *reinterpret_cast<const uint2*>(sku + nb + ch);
            const float4 sk = bfp4(skw.x, skw.y);
            *reinterpret_cast<float4*>(out + nb + ch) =
                make_float4(fmaf(acc0, inv, sk.x), fmaf(acc1, inv, sk.y),
                            fmaf(acc2, inv, sk.z), fmaf(acc3, inv, sk.w));
        }
    }
}

extern "C" void kernel_launch(void* const* d_in, const int* in_sizes, int n_in,
                              void* d_out, int out_size, void* d_ws, size_t ws_size,
                              hipStream_t stream) {
    const float* x     = (const float*)d_in[0];
    const int*   ei    = (const int*)  d_in[1];
    const float* eattr = (const float*)d_in[2];
    const float* Wq1 = (const float*)d_in[3],  *bq1 = (const float*)d_in[4];
    const float* Wk1 = (const float*)d_in[5],  *bk1 = (const float*)d_in[6];
    const float* Wv1 = (const float*)d_in[7],  *bv1 = (const float*)d_in[8];
    const float* We1 = (const float*)d_in[9];
    const float* Ws1 = (const float*)d_in[10], *bs1 = (const float*)d_in[11];
    const float* Wq2 = (const float*)d_in[12], *bq2 = (const float*)d_in[13];
    const float* Wk2 = (const float*)d_in[14], *bk2 = (const float*)d_in[15];
    const float* Wv2 = (const float*)d_in[16], *bv2 = (const float*)d_in[17];
    const float* We2 = (const float*)d_in[18];
    const float* Ws2 = (const float*)d_in[19], *bs2 = (const float*)d_in[20];

    const int* srcp = ei;
    const int* dstp = ei + NE;

    // workspace layout — every buffer 512B-aligned
    char* base = (char*)d_ws;
    size_t o = 0;
    auto alloc = [&](size_t bytes) -> void* {
        void* p = base + o;
        o = (o + bytes + 511) & ~(size_t)511;
        return p;
    };
    float* wq1   = (float*)alloc((size_t)NN * 32 * 4);
    float* wq2   = (float*)alloc((size_t)NN * 16 * 4);
    float* bcat1 = (float*)alloc(544 * 4);
    float* bcat2 = (float*)alloc(272 * 4);
    int*  blkcnt = (int*)alloc((size_t)NCB * NBKT * 4);
    uint32_t* sidx = (uint32_t*)alloc((size_t)NE * 4);
    int*  bstart = (int*)alloc((NBKT + 1) * 4);
    int*  srcs   = (int*)alloc((size_t)NE * 4);
    int*  off    = (int*)alloc((size_t)(NN + 1) * 4);
    __hip_bfloat16* eap1 = (__hip_bfloat16*)alloc((size_t)NE * 16 * 2);
    __hip_bfloat16* eap  = (__hip_bfloat16*)alloc((size_t)NE * 16 * 2);
    __hip_bfloat16* q1b  = (__hip_bfloat16*)alloc((size_t)NN * 128 * 2);
    __hip_bfloat16* sk1b = (__hip_bfloat16*)alloc((size_t)NN * 128 * 2);
    __hip_bfloat16* hb   = (__hip_bfloat16*)alloc((size_t)NN * 128 * 2);
    __hip_bfloat16* kv1  = (__hip_bfloat16*)alloc((size_t)NN * 256 * 2);
    __hip_bfloat16* Wp1  = (__hip_bfloat16*)alloc((size_t)34 * 2048 * 2);
    __hip_bfloat16* Wp2  = (__hip_bfloat16*)alloc((size_t)17 * 2048 * 2);
    // layer-2 aliases (dead layer-1 buffers, stream-ordered)
    __hip_bfloat16* q2b  = q1b;
    __hip_bfloat16* sk2b = sk1b;
    __hip_bfloat16* kv2  = kv1;

    // 1. prep: bucket histogram + weight packing (no global atomics)
    prep<<<PB_PA2, 256, 0, stream>>>(dstp, blkcnt,
        Wq1, Wk1, Wv1, Ws1, bq1, bk1, bv1, bs1, We1,
        Wq2, Wk2, Wv2, Ws2, bq2, bk2, bv2, bs2, We2,
        Wp1, bcat1, Wp2, bcat2);

    // 2. passC: LDS-staged bucket sort carrying sidx + bf16 ea (burst writes)
    passC<<<NCB, 1024, 0, stream>>>(dstp, srcp, eattr, blkcnt, sidx, eap1, bstart);

    // 3. passD ∥ layer-1 GEMM: node sort + eap permute (hidden under gemm1)
    passD_mid<<<DB_ALL, 1024, 0, stream>>>(sidx, eap1, bstart, off, srcs, eap,
                                           x, Wp1, bcat1, q1b, kv1, sk1b, wq1);

    // 4. layer 1 aggregation (persistent blocks)
    agg_l1<<<AGG_GRID, 256, 0, stream>>>(off, srcs, eap, We1, wq1, q1b, kv1, sk1b, hb);

    // 5. layer 2 GEMM
    gemm_fused<64, 16, false><<<NN / 16, 256, 0, stream>>>(
        hb, Wp2, bcat2, q2b, kv2, sk2b, wq2);

    // 6. layer 2 aggregation (persistent blocks)
    agg_l2<<<AGG_GRID, 256, 0, stream>>>(off, srcs, eap, We2, wq2, q2b, kv2, sk2b, (float*)d_out);
}

// Round 21
// 249.629 us; speedup vs baseline: 1.0419x; 1.0419x over previous
//
#include <hip/hip_runtime.h>
#include <hip/hip_bf16.h>

#define NN 50000
#define NE 800000
#define NBKT 196          // bucket = dst >> 8 (256 nodes per bucket)
#define EPB 2048          // edges per histogram/sort block
#define NCB 391           // ceil(NE / EPB)

// prep kernel block ranges
#define PB_BH   NCB
#define PB_PW1  (PB_BH + 32)
#define PB_PW2  (PB_PW1 + 16)
#define PB_PA1  (PB_PW2 + 2)
#define PB_PA2  (PB_PA1 + 1)

// passD block ranges (bucket node-sort ∥ layer-1 GEMM, 1024-thread blocks)
#define DB_BKT  NBKT
#define DB_GT   782            // ceil(3125 gemm tiles / 4)
#define DB_ALL  (DB_BKT + DB_GT)

typedef __attribute__((ext_vector_type(8))) short bf16x8;
typedef __attribute__((ext_vector_type(4))) float f32x4;

__device__ __forceinline__ float2 bfp(uint32_t u) {
    union { uint32_t i; float f; } lo, hi;
    lo.i = u << 16;
    hi.i = u & 0xffff0000u;
    return make_float2(lo.f, hi.f);
}
__device__ __forceinline__ float bf1(uint16_t u) {
    union { uint32_t i; float f; } x; x.i = ((uint32_t)u) << 16; return x.f;
}
__device__ __forceinline__ float4 bfp4(uint32_t a, uint32_t b) {
    const float2 lo = bfp(a), hi = bfp(b);
    return make_float4(lo.x, lo.y, hi.x, hi.y);
}

// ---------------------------------------------------------------------------
// prep: per-block bucket histogram + weight packing
// ---------------------------------------------------------------------------
template<int M>
__device__ __forceinline__ void pack_w_dev(
    int t, const float* __restrict__ Wq, const float* __restrict__ Wk,
    const float* __restrict__ Wv, const float* __restrict__ Wsk,
    const float* __restrict__ bq, const float* __restrict__ bk,
    const float* __restrict__ bv, const float* __restrict__ bsk,
    __hip_bfloat16* __restrict__ Wp, float* __restrict__ bcat)
{
    constexpr int NFQ = M / 16;
    constexpr int NF_TOT = 4 * NFQ;
    if (t >= 4 * NF_TOT * 64) return;
    const int l  = t & 63;
    const int fg = (t >> 6) % NF_TOT;
    const int s  = t / (64 * NF_TOT);
    const int sec = fg / NFQ;
    const int fl  = fg % NFQ;
    const float* W = sec == 0 ? Wq : sec == 1 ? Wk : sec == 2 ? Wv : Wsk;
    const int col = fl * 16 + (l & 15);
    const int k0  = s * 32 + (l >> 4) * 8;
    __hip_bfloat16 tmp[8];
    #pragma unroll
    for (int j = 0; j < 8; ++j) tmp[j] = __float2bfloat16(W[(size_t)(k0 + j) * M + col]);
    *reinterpret_cast<uint4*>(Wp + ((size_t)(fg * 4 + s) * 64 + l) * 8) =
        *reinterpret_cast<const uint4*>(tmp);
    if (s == 0 && (l >> 4) == 0) {
        const float* B = sec == 0 ? bq : sec == 1 ? bk : sec == 2 ? bv : bsk;
        bcat[fg * 16 + (l & 15)] = B[col];
    }
}

template<int MW, int MO>
__device__ __forceinline__ void pack_wq_dev(
    int t, const float* __restrict__ Wq, const float* __restrict__ We,
    const float* __restrict__ bq,
    __hip_bfloat16* __restrict__ Ap, float* __restrict__ B0)
{
    constexpr int NF = MO / 16;
    if (t >= 4 * NF * 64) return;
    const int l  = t & 63;
    const int fg = (t >> 6) % NF;
    const int s  = t / (64 * NF);
    const int col = fg * 16 + (l & 15);
    const int h = col >> 4;
    const int r = col & 15;
    const int k0 = s * 32 + (l >> 4) * 8;
    __hip_bfloat16 tmp[8];
    #pragma unroll
    for (int jj = 0; jj < 8; ++jj) {
        float acc = 0.f;
        for (int c = 0; c < 64; ++c)
            acc += Wq[(size_t)(k0 + jj) * MW + h * 64 + c] * We[r * MW + h * 64 + c];
        tmp[jj] = __float2bfloat16(acc * 0.125f);
    }
    *reinterpret_cast<uint4*>(Ap + ((size_t)(fg * 4 + s) * 64 + l) * 8) =
        *reinterpret_cast<const uint4*>(tmp);
    if (s == 0 && (l >> 4) == 0) {
        float acc = 0.f;
        for (int c = 0; c < 64; ++c) acc += bq[h * 64 + c] * We[r * MW + h * 64 + c];
        B0[col] = acc * 0.125f;
    }
}

__global__ __launch_bounds__(256)
void prep(const int* __restrict__ dstp, int* __restrict__ blkcnt,
          const float* Wq1, const float* Wk1, const float* Wv1, const float* Ws1,
          const float* bq1, const float* bk1, const float* bv1, const float* bs1,
          const float* We1,
          const float* Wq2, const float* Wk2, const float* Wv2, const float* Ws2,
          const float* bq2, const float* bk2, const float* bv2, const float* bs2,
          const float* We2,
          __hip_bfloat16* Wp1, float* bcat1,
          __hip_bfloat16* Wp2, float* bcat2)
{
    const int b = blockIdx.x;
    const int t = threadIdx.x;
    if (b < PB_BH) {
        __shared__ int bins[NBKT];
        if (t < NBKT) bins[t] = 0;
        __syncthreads();
        const int e0 = b * EPB;
        const int nedge = min(EPB, NE - e0);
        for (int j = 0; j < EPB / 256; ++j) {
            const int idx = t + j * 256;
            if (idx < nedge) atomicAdd(&bins[dstp[e0 + idx] >> 8], 1);
        }
        __syncthreads();
        if (t < NBKT) blkcnt[b * NBKT + t] = bins[t];
    } else if (b < PB_PW1) {
        pack_w_dev<128>((b - PB_BH) * 256 + t, Wq1, Wk1, Wv1, Ws1,
                        bq1, bk1, bv1, bs1, Wp1, bcat1);
    } else if (b < PB_PW2) {
        pack_w_dev<64>((b - PB_PW1) * 256 + t, Wq2, Wk2, Wv2, Ws2,
                       bq2, bk2, bv2, bs2, Wp2, bcat2);
    } else if (b < PB_PA1) {
        pack_wq_dev<128, 32>((b - PB_PW2) * 256 + t, Wq1, We1, bq1,
                             Wp1 + (size_t)32 * 2048, bcat1 + 512);
    } else {
        pack_wq_dev<64, 16>((b - PB_PA1) * 256 + t, Wq2, We2, bq2,
                            Wp2 + (size_t)16 * 2048, bcat2 + 256);
    }
}

// ---------------------------------------------------------------------------
// passC (1024 threads, EPB=2048): LDS-staged bucket sort carrying sidx + bf16
// ea. Sequential reads; burst write-out -> full-line writes.
// sbuf entry: src(16) | dstlow(8)<<16 | bkt(8)<<24. sidx output: low 24 bits.
// ---------------------------------------------------------------------------
__global__ __launch_bounds__(1024)
void passC(const int* __restrict__ dstp, const int* __restrict__ srcp,
           const float* __restrict__ ea, const int* __restrict__ blkcnt,
           uint32_t* __restrict__ sidx, __hip_bfloat16* __restrict__ eap1,
           int* __restrict__ bucket_start)
{
    __shared__ int gbase[NBKT];
    __shared__ int lofs0[NBKT];
    __shared__ int lcur[NBKT];
    __shared__ int stmp[256];
    __shared__ uint32_t sbuf[EPB];
    __shared__ uint4 eb0[EPB];
    __shared__ uint4 eb1[EPB];

    const int blk = blockIdx.x;
    const int t = threadIdx.x;

    int partial = 0, total = 0;
    if (t < NBKT) {
        for (int b = 0; b < NCB; ++b) {
            const int v = blkcnt[b * NBKT + t];
            partial += (b < blk) ? v : 0;
            total += v;
        }
    }
    if (t < 256) stmp[t] = (t < NBKT) ? total : 0;
    __syncthreads();
    for (int d = 1; d < 256; d <<= 1) {
        const int v = (t < 256 && t >= d) ? stmp[t - d] : 0;
        __syncthreads();
        if (t < 256) stmp[t] += v;
        __syncthreads();
    }
    if (t < NBKT) {
        const int bstart = stmp[t] - total;
        gbase[t] = bstart + partial;
        if (blk == 0) {
            bucket_start[t] = bstart;
            if (t == NBKT - 1) bucket_start[NBKT] = stmp[t];
        }
    }

    if (t < NBKT) lcur[t] = 0;
    __syncthreads();
    const int e0 = blk * EPB;
    const int nedge = min(EPB, NE - e0);
    for (int j = 0; j < EPB / 1024; ++j) {
        const int idx = t + j * 1024;
        if (idx < nedge) atomicAdd(&lcur[dstp[e0 + idx] >> 8], 1);
    }
    __syncthreads();
    if (t < 256) stmp[t] = (t < NBKT) ? lcur[t] : 0;
    __syncthreads();
    int own = 0;
    if (t < 256) own = stmp[t];
    for (int d = 1; d < 256; d <<= 1) {
        const int v = (t < 256 && t >= d) ? stmp[t - d] : 0;
        __syncthreads();
        if (t < 256) stmp[t] += v;
        __syncthreads();
    }
    if (t < NBKT) { lofs0[t] = stmp[t] - own; lcur[t] = stmp[t] - own; }
    __syncthreads();

    for (int j = 0; j < EPB / 1024; ++j) {
        const int idx = t + j * 1024;
        if (idx < nedge) {
            const int e = e0 + idx;
            const int d_ = dstp[e];
            const int bkt = d_ >> 8;
            const int q = atomicAdd(&lcur[bkt], 1);
            sbuf[q] = (uint32_t)srcp[e] | ((uint32_t)(d_ & 255) << 16)
                      | ((uint32_t)bkt << 24);
            const float4* ea4 = reinterpret_cast<const float4*>(ea) + (size_t)e * 4;
            const float4 a0 = ea4[0], a1 = ea4[1], a2 = ea4[2], a3 = ea4[3];
            const float af[16] = {a0.x,a0.y,a0.z,a0.w, a1.x,a1.y,a1.z,a1.w,
                                  a2.x,a2.y,a2.z,a2.w, a3.x,a3.y,a3.z,a3.w};
            __hip_bfloat16 tmp[16];
            #pragma unroll
            for (int r = 0; r < 16; ++r) tmp[r] = __float2bfloat16(af[r]);
            eb0[q] = *reinterpret_cast<const uint4*>(&tmp[0]);
            eb1[q] = *reinterpret_cast<const uint4*>(&tmp[8]);
        }
    }
    __syncthreads();

    for (int j = 0; j < EPB / 1024; ++j) {
        const int q = t + j * 1024;
        if (q < nedge) {
            const uint32_t v = sbuf[q];
            const int bkt = v >> 24;
            const int gpos = gbase[bkt] + (q - lofs0[bkt]);
            sidx[gpos] = v & 0x00ffffffu;
            uint4* dp = reinterpret_cast<uint4*>(eap1 + (size_t)gpos * 16);
            dp[0] = eb0[q];
            dp[1] = eb1[q];
        }
    }
}

// ---------------------------------------------------------------------------
// Fused MFMA node GEMM (device body, 256-thread granule).
// kv stored INTERLEAVED (per 4-channel group: 8B k then 8B v).
// ---------------------------------------------------------------------------
template<int M, int MO, bool F32IN>
__device__ __forceinline__
void gemm_dev(int blk, int tid, const void* __restrict__ xin,
              const __hip_bfloat16* __restrict__ Wp,
              const float* __restrict__ bcat,
              __hip_bfloat16* __restrict__ q, __hip_bfloat16* __restrict__ kv,
              __hip_bfloat16* __restrict__ skip, float* __restrict__ wqo)
{
    constexpr int NF_TOT = (4 * M + MO) / 16;
    constexpr int NFW = (NF_TOT + 3) / 4;
    const int wid  = tid >> 6;
    const int l    = tid & 63;
    const int row0 = blk * 16;
    const int rowg = row0 + (l & 15);
    const int kb   = l >> 4;

    f32x4 acc[NFW];
    #pragma unroll
    for (int f = 0; f < NFW; ++f) acc[f] = f32x4{0.f, 0.f, 0.f, 0.f};

    const bf16x8* wp8 = reinterpret_cast<const bf16x8*>(Wp);
    #pragma unroll
    for (int s = 0; s < 4; ++s) {
        bf16x8 a;
        if constexpr (F32IN) {
            const float* xf = (const float*)xin;
            const float4 a0 = *reinterpret_cast<const float4*>(
                xf + (size_t)rowg * 128 + s * 32 + kb * 8);
            const float4 a1 = *reinterpret_cast<const float4*>(
                xf + (size_t)rowg * 128 + s * 32 + kb * 8 + 4);
            union { __hip_bfloat16 h[8]; bf16x8 v; } u;
            u.h[0] = __float2bfloat16(a0.x); u.h[1] = __float2bfloat16(a0.y);
            u.h[2] = __float2bfloat16(a0.z); u.h[3] = __float2bfloat16(a0.w);
            u.h[4] = __float2bfloat16(a1.x); u.h[5] = __float2bfloat16(a1.y);
            u.h[6] = __float2bfloat16(a1.z); u.h[7] = __float2bfloat16(a1.w);
            a = u.v;
        } else {
            const __hip_bfloat16* xb = (const __hip_bfloat16*)xin;
            a = *reinterpret_cast<const bf16x8*>(xb + (size_t)rowg * 128 + s * 32 + kb * 8);
        }
        #pragma unroll
        for (int f = 0; f < NFW; ++f) {
            const int fg = wid + 4 * f;
            if (fg < NF_TOT)
                acc[f] = __builtin_amdgcn_mfma_f32_16x16x32_bf16(
                    a, wp8[(size_t)(fg * 4 + s) * 64 + l], acc[f], 0, 0, 0);
        }
    }

    const int cl = l & 15;
    #pragma unroll
    for (int f = 0; f < NFW; ++f) {
        const int fg = wid + 4 * f;
        if (fg >= NF_TOT) continue;
        const int cg = fg * 16 + cl;
        const float bb = bcat[cg];
        #pragma unroll
        for (int j = 0; j < 4; ++j) {
            const int row = row0 + kb * 4 + j;
            const float val = acc[f][j] + bb;
            if (cg < M) {
                q[(size_t)row * M + cg] = __float2bfloat16(val * 0.125f);
            } else if (cg < 2 * M) {
                const int c = cg - M;
                kv[(size_t)row * 2 * M + (c >> 2) * 8 + (c & 3)] = __float2bfloat16(val);
            } else if (cg < 3 * M) {
                const int c = cg - 2 * M;
                kv[(size_t)row * 2 * M + (c >> 2) * 8 + 4 + (c & 3)] = __float2bfloat16(val);
            } else if (cg < 4 * M) {
                skip[(size_t)row * M + (cg - 3 * M)] = __float2bfloat16(val);
            } else {
                wqo[(size_t)row * MO + (cg - 4 * M)] = val;
            }
        }
    }
}

template<int M, int MO, bool F32IN>
__global__ __launch_bounds__(256)
void gemm_fused(const void* __restrict__ xin,
                const __hip_bfloat16* __restrict__ Wp,
                const float* __restrict__ bcat,
                __hip_bfloat16* __restrict__ q, __hip_bfloat16* __restrict__ kv,
                __hip_bfloat16* __restrict__ skip, float* __restrict__ wqo)
{
    gemm_dev<M, MO, F32IN>(blockIdx.x, threadIdx.x, xin, Wp, bcat, q, kv, skip, wqo);
}

// ---------------------------------------------------------------------------
// passD ∥ gemm1 (1024-thread blocks). Bucket blocks: node-level counting sort;
// writes srcs[p] AND permutes eap1[i] -> eap[p] (sequential reads, dense
// in-bucket writes, L2-absorbed). Gemm blocks: 4 GEMM tiles each.
// ---------------------------------------------------------------------------
__global__ __launch_bounds__(1024)
void passD_mid(const uint32_t* __restrict__ sidx, const __hip_bfloat16* __restrict__ eap1,
               const int* __restrict__ bucket_start,
               int* __restrict__ off, int* __restrict__ srcs,
               __hip_bfloat16* __restrict__ eap,
               const float* __restrict__ x, const __hip_bfloat16* __restrict__ Wp1,
               const float* __restrict__ bcat1, __hip_bfloat16* __restrict__ q1b,
               __hip_bfloat16* __restrict__ kv1, __hip_bfloat16* __restrict__ sk1b,
               float* __restrict__ wq1)
{
    __shared__ int nbins[256];
    __shared__ int ncur[256];
    __shared__ int stmp[256];

    if (blockIdx.x >= DB_BKT) {
        const int tile = (blockIdx.x - DB_BKT) * 4 + (threadIdx.x >> 8);
        if (tile < 3125)
            gemm_dev<128, 32, true>(tile, threadIdx.x & 255, x, Wp1, bcat1,
                                    q1b, kv1, sk1b, wq1);
        return;
    }

    const int b = blockIdx.x;
    const int t = threadIdx.x;
    const int bs = bucket_start[b];
    const int be = bucket_start[b + 1];

    if (t < 256) nbins[t] = 0;
    __syncthreads();
    for (int i = bs + t; i < be; i += 1024)
        atomicAdd(&nbins[(sidx[i] >> 16) & 255], 1);
    __syncthreads();

    if (t < 256) stmp[t] = nbins[t];
    __syncthreads();
    for (int d = 1; d < 256; d <<= 1) {
        const int v = (t < 256 && t >= d) ? stmp[t - d] : 0;
        __syncthreads();
        if (t < 256) stmp[t] += v;
        __syncthreads();
    }
    if (t < 256) {
        const int own = nbins[t];
        const int excl = stmp[t] - own;
        ncur[t] = excl;
        const int node = b * 256 + t;
        if (node <= NN) off[node] = bs + excl;
    }
    __syncthreads();

    for (int i = bs + t; i < be; i += 1024) {
        const uint32_t v = sidx[i];
        const int dl = (v >> 16) & 255;
        const int p = bs + atomicAdd(&ncur[dl], 1);
        srcs[p] = (int)(v & 0xffffu);
        const uint4* sp = reinterpret_cast<const uint4*>(eap1 + (size_t)i * 16);
        uint4* dp = reinterpret_cast<uint4*>(eap + (size_t)p * 16);
        dp[0] = sp[0];
        dp[1] = sp[1];
    }
}

// ---------------------------------------------------------------------------
// Layer-1 aggregation (srcs + node-sorted bf16 eap). One wave per node; lane
// owns 4 channels; interleaved kv -> ONE uint4 gather per edge per lane;
// 2 edges per pass (one per 32-half), x4 unrolled.
// ---------------------------------------------------------------------------
__global__ __launch_bounds__(256)
void agg_l1(const int* __restrict__ off, const int* __restrict__ srcs,
            const __hip_bfloat16* __restrict__ eap,
            const float* __restrict__ We,              // [16,128]
            const float* __restrict__ wq,              // [N,32]
            const __hip_bfloat16* __restrict__ qb,     // [N,128] bf16, pre-scaled
            const __hip_bfloat16* __restrict__ kv,     // [N,256] interleaved k|v
            const __hip_bfloat16* __restrict__ skb,    // [N,128] bf16
            __hip_bfloat16* __restrict__ hb)
{
    __shared__ float wes[16 * 128];
    for (int i = threadIdx.x; i < 16 * 128; i += 256) wes[i] = We[i];
    __syncthreads();

    const int node = blockIdx.x * 4 + (threadIdx.x >> 6);
    const int lane = threadIdx.x & 63;
    const int hf   = lane >> 5;
    const int hl   = lane & 31;
    const int g    = lane & 15;
    const int ch   = hl * 4;

    const size_t nb = (size_t)node * 128;
    const uint16_t* qu = reinterpret_cast<const uint16_t*>(qb);
    const uint2 qw = *reinterpret_cast<const uint2*>(qu + nb + ch);
    const float4 qv = bfp4(qw.x, qw.y);
    const float wqv = wq[(size_t)node * 32 + (hl >> 4) * 16 + g];
    const uint16_t* kvu = reinterpret_cast<const uint16_t*>(kv);
    const uint16_t* eau = reinterpret_cast<const uint16_t*>(eap);

    float acc0 = 0.f, acc1 = 0.f, acc2 = 0.f, acc3 = 0.f, den = 0.f, eacc = 0.f;
    const int beg = off[node], end = off[node + 1];

    for (int i = beg; i < end; i += 8) {
        const int ii0 = i + hf,     ii1 = i + 2 + hf;
        const int ii2 = i + 4 + hf, ii3 = i + 6 + hf;
        const bool v0 = ii0 < end, v1 = ii1 < end, v2 = ii2 < end, v3 = ii3 < end;
        const int i0 = v0 ? ii0 : beg, i1 = v1 ? ii1 : beg;
        const int i2 = v2 ? ii2 : beg, i3 = v3 ? ii3 : beg;
        const int s0 = srcs[i0], s1 = srcs[i1], s2 = srcs[i2], s3 = srcs[i3];
        const uint4 x0 = *reinterpret_cast<const uint4*>(kvu + (size_t)s0 * 256 + hl * 8);
        const uint4 x1 = *reinterpret_cast<const uint4*>(kvu + (size_t)s1 * 256 + hl * 8);
        const uint4 x2 = *reinterpret_cast<const uint4*>(kvu + (size_t)s2 * 256 + hl * 8);
        const uint4 x3 = *reinterpret_cast<const uint4*>(kvu + (size_t)s3 * 256 + hl * 8);
        const float ea0 = bf1(eau[(size_t)i0 * 16 + g]);
        const float ea1 = bf1(eau[(size_t)i1 * 16 + g]);
        const float ea2 = bf1(eau[(size_t)i2 * 16 + g]);
        const float ea3 = bf1(eau[(size_t)i3 * 16 + g]);
        const float4 k0 = bfp4(x0.x, x0.y), k1 = bfp4(x1.x, x1.y);
        const float4 k2 = bfp4(x2.x, x2.y), k3 = bfp4(x3.x, x3.y);
        float p0 = fmaf(qv.x, k0.x, fmaf(qv.y, k0.y,
                   fmaf(qv.z, k0.z, fmaf(qv.w, k0.w, ea0 * wqv))));
        float p1 = fmaf(qv.x, k1.x, fmaf(qv.y, k1.y,
                   fmaf(qv.z, k1.z, fmaf(qv.w, k1.w, ea1 * wqv))));
        float p2 = fmaf(qv.x, k2.x, fmaf(qv.y, k2.y,
                   fmaf(qv.z, k2.z, fmaf(qv.w, k2.w, ea2 * wqv))));
        float p3 = fmaf(qv.x, k3.x, fmaf(qv.y, k3.y,
                   fmaf(qv.z, k3.z, fmaf(qv.w, k3.w, ea3 * wqv))));
        #pragma unroll
        for (int m = 1; m < 16; m <<= 1) {
            p0 += __shfl_xor(p0, m, 64);
            p1 += __shfl_xor(p1, m, 64);
            p2 += __shfl_xor(p2, m, 64);
            p3 += __shfl_xor(p3, m, 64);
        }
        const float ex0 = v0 ? __expf(p0) : 0.f;
        const float ex1 = v1 ? __expf(p1) : 0.f;
        const float ex2 = v2 ? __expf(p2) : 0.f;
        const float ex3 = v3 ? __expf(p3) : 0.f;
        const float4 w0 = bfp4(x0.z, x0.w), w1 = bfp4(x1.z, x1.w);
        const float4 w2 = bfp4(x2.z, x2.w), w3 = bfp4(x3.z, x3.w);
        acc0 = fmaf(ex0, w0.x, fmaf(ex1, w1.x, fmaf(ex2, w2.x, fmaf(ex3, w3.x, acc0))));
        acc1 = fmaf(ex0, w0.y, fmaf(ex1, w1.y, fmaf(ex2, w2.y, fmaf(ex3, w3.y, acc1))));
        acc2 = fmaf(ex0, w0.z, fmaf(ex1, w1.z, fmaf(ex2, w2.z, fmaf(ex3, w3.z, acc2))));
        acc3 = fmaf(ex0, w0.w, fmaf(ex1, w1.w, fmaf(ex2, w2.w, fmaf(ex3, w3.w, acc3))));
        den += (ex0 + ex1) + (ex2 + ex3);
        eacc = fmaf(ex0, ea0, fmaf(ex1, ea1, fmaf(ex2, ea2, fmaf(ex3, ea3, eacc))));
    }

    acc0 += __shfl_xor(acc0, 32, 64);
    acc1 += __shfl_xor(acc1, 32, 64);
    acc2 += __shfl_xor(acc2, 32, 64);
    acc3 += __shfl_xor(acc3, 32, 64);
    den  += __shfl_xor(den, 32, 64);
    eacc += __shfl_xor(eacc, 32, 64);

    const int gb = lane & 16;
    #pragma unroll
    for (int r = 0; r < 16; ++r) {
        const float er = __shfl(eacc, gb + r, 64);
        const float4 w = *reinterpret_cast<const float4*>(&wes[r * 128 + ch]);
        acc0 = fmaf(er, w.x, acc0);
        acc1 = fmaf(er, w.y, acc1);
        acc2 = fmaf(er, w.z, acc2);
        acc3 = fmaf(er, w.w, acc3);
    }

    if (hf == 0) {
        const float inv = 1.f / (den + 1e-16f);
        const uint16_t* sku = reinterpret_cast<const uint16_t*>(skb);
        const uint2 skw = *reinterpret_cast<const uint2*>(sku + nb + ch);
        const float4 sk = bfp4(skw.x, skw.y);
        __hip_bfloat16 hp[4] = {
            __float2bfloat16(fmaxf(fmaf(acc0, inv, sk.x), 0.f)),
            __float2bfloat16(fmaxf(fmaf(acc1, inv, sk.y), 0.f)),
            __float2bfloat16(fmaxf(fmaf(acc2, inv, sk.z), 0.f)),
            __float2bfloat16(fmaxf(fmaf(acc3, inv, sk.w), 0.f))};
        *reinterpret_cast<uint2*>(hb + nb + ch) = *reinterpret_cast<const uint2*>(hp);
    }
}

// ---------------------------------------------------------------------------
// Layer-2 aggregation. Lane owns 4 channels; 4 edges per pass (16 lanes each),
// x2 unrolled (8 edges in flight). Out f32.
// ---------------------------------------------------------------------------
__global__ __launch_bounds__(256)
void agg_l2(const int* __restrict__ off, const int* __restrict__ srcs,
            const __hip_bfloat16* __restrict__ eap,
            const float* __restrict__ We,              // [16,64]
            const float* __restrict__ wq,              // [N,16]
            const __hip_bfloat16* __restrict__ qb,     // [N,64] bf16, pre-scaled
            const __hip_bfloat16* __restrict__ kv,     // [N,128] interleaved k|v
            const __hip_bfloat16* __restrict__ skb,    // [N,64] bf16
            float* __restrict__ out)
{
    __shared__ float wes[16 * 64];
    for (int i = threadIdx.x; i < 16 * 64; i += 256) wes[i] = We[i];
    __syncthreads();

    const int node = blockIdx.x * 4 + (threadIdx.x >> 6);
    const int lane = threadIdx.x & 63;
    const int grp  = lane >> 4;
    const int g    = lane & 15;
    const int ch   = g * 4;

    const size_t nb = (size_t)node * 64;
    const uint16_t* qu = reinterpret_cast<const uint16_t*>(qb);
    const uint2 qw = *reinterpret_cast<const uint2*>(qu + nb + ch);
    const float4 qv = bfp4(qw.x, qw.y);
    const float wqv = wq[(size_t)node * 16 + g];
    const uint16_t* kvu = reinterpret_cast<const uint16_t*>(kv);
    const uint16_t* eau = reinterpret_cast<const uint16_t*>(eap);

    float acc0 = 0.f, acc1 = 0.f, acc2 = 0.f, acc3 = 0.f, den = 0.f, eacc = 0.f;
    const int beg = off[node], end = off[node + 1];

    for (int i = beg; i < end; i += 8) {
        const int ii0 = i + grp, ii1 = i + 4 + grp;
        const bool v0 = ii0 < end, v1 = ii1 < end;
        const int i0 = v0 ? ii0 : beg, i1 = v1 ? ii1 : beg;
        const int s0 = srcs[i0], s1 = srcs[i1];
        const uint4 x0 = *reinterpret_cast<const uint4*>(kvu + (size_t)s0 * 128 + g * 8);
        const uint4 x1 = *reinterpret_cast<const uint4*>(kvu + (size_t)s1 * 128 + g * 8);
        const float ea0 = bf1(eau[(size_t)i0 * 16 + g]);
        const float ea1 = bf1(eau[(size_t)i1 * 16 + g]);
        const float4 k0 = bfp4(x0.x, x0.y), k1 = bfp4(x1.x, x1.y);
        float p0 = fmaf(qv.x, k0.x, fmaf(qv.y, k0.y,
                   fmaf(qv.z, k0.z, fmaf(qv.w, k0.w, ea0 * wqv))));
        float p1 = fmaf(qv.x, k1.x, fmaf(qv.y, k1.y,
                   fmaf(qv.z, k1.z, fmaf(qv.w, k1.w, ea1 * wqv))));
        #pragma unroll
        for (int m = 1; m < 16; m <<= 1) {
            p0 += __shfl_xor(p0, m, 64);
            p1 += __shfl_xor(p1, m, 64);
        }
        const float ex0 = v0 ? __expf(p0) : 0.f;
        const float ex1 = v1 ? __expf(p1) : 0.f;
        const float4 w0 = bfp4(x0.z, x0.w), w1 = bfp4(x1.z, x1.w);
        acc0 = fmaf(ex0, w0.x, fmaf(ex1, w1.x, acc0));
        acc1 = fmaf(ex0, w0.y, fmaf(ex1, w1.y, acc1));
        acc2 = fmaf(ex0, w0.z, fmaf(ex1, w1.z, acc2));
        acc3 = fmaf(ex0, w0.w, fmaf(ex1, w1.w, acc3));
        den += ex0 + ex1;
        eacc = fmaf(ex0, ea0, fmaf(ex1, ea1, eacc));
    }

    acc0 += __shfl_xor(acc0, 16, 64);  acc0 += __shfl_xor(acc0, 32, 64);
    acc1 += __shfl_xor(acc1, 16, 64);  acc1 += __shfl_xor(acc1, 32, 64);
    acc2 += __shfl_xor(acc2, 16, 64);  acc2 += __shfl_xor(acc2, 32, 64);
    acc3 += __shfl_xor(acc3, 16, 64);  acc3 += __shfl_xor(acc3, 32, 64);
    den  += __shfl_xor(den, 16, 64);   den  += __shfl_xor(den, 32, 64);
    eacc += __shfl_xor(eacc, 16, 64);  eacc += __shfl_xor(eacc, 32, 64);

    #pragma unroll
    for (int r = 0; r < 16; ++r) {
        const float er = __shfl(eacc, r, 64);
        const float4 w = *reinterpret_cast<const float4*>(&wes[r * 64 + ch]);
        acc0 = fmaf(er, w.x, acc0);
        acc1 = fmaf(er, w.y, acc1);
        acc2 = fmaf(er, w.z, acc2);
        acc3 = fmaf(er, w.w, acc3);
    }

    if (lane < 16) {
        const float inv = 1.f / (den + 1e-16f);
        const uint16_t* sku = reinterpret_cast<const uint16_t*>(skb);
        const uint2 skw = *reinterpret_cast<const uint2*>(sku + nb + ch);
        const float4 sk = bfp4(skw.x, skw.y);
        *reinterpret_cast<float4*>(out + nb + ch) =
            make_float4(fmaf(acc0, inv, sk.x), fmaf(acc1, inv, sk.y),
                        fmaf(acc2, inv, sk.z), fmaf(acc3, inv, sk.w));
    }
}

extern "C" void kernel_launch(void* const* d_in, const int* in_sizes, int n_in,
                              void* d_out, int out_size, void* d_ws, size_t ws_size,
                              hipStream_t stream) {
    const float* x     = (const float*)d_in[0];
    const int*   ei    = (const int*)  d_in[1];
    const float* eattr = (const float*)d_in[2];
    const float* Wq1 = (const float*)d_in[3],  *bq1 = (const float*)d_in[4];
    const float* Wk1 = (const float*)d_in[5],  *bk1 = (const float*)d_in[6];
    const float* Wv1 = (const float*)d_in[7],  *bv1 = (const float*)d_in[8];
    const float* We1 = (const float*)d_in[9];
    const float* Ws1 = (const float*)d_in[10], *bs1 = (const float*)d_in[11];
    const float* Wq2 = (const float*)d_in[12], *bq2 = (const float*)d_in[13];
    const float* Wk2 = (const float*)d_in[14], *bk2 = (const float*)d_in[15];
    const float* Wv2 = (const float*)d_in[16], *bv2 = (const float*)d_in[17];
    const float* We2 = (const float*)d_in[18];
    const float* Ws2 = (const float*)d_in[19], *bs2 = (const float*)d_in[20];

    const int* srcp = ei;
    const int* dstp = ei + NE;

    // workspace layout — every buffer 512B-aligned
    char* base = (char*)d_ws;
    size_t o = 0;
    auto alloc = [&](size_t bytes) -> void* {
        void* p = base + o;
        o = (o + bytes + 511) & ~(size_t)511;
        return p;
    };
    float* wq1   = (float*)alloc((size_t)NN * 32 * 4);
    float* wq2   = (float*)alloc((size_t)NN * 16 * 4);
    float* bcat1 = (float*)alloc(544 * 4);
    float* bcat2 = (float*)alloc(272 * 4);
    int*  blkcnt = (int*)alloc((size_t)NCB * NBKT * 4);
    uint32_t* sidx = (uint32_t*)alloc((size_t)NE * 4);
    int*  bstart = (int*)alloc((NBKT + 1) * 4);
    int*  srcs   = (int*)alloc((size_t)NE * 4);
    int*  off    = (int*)alloc((size_t)(NN + 1) * 4);
    __hip_bfloat16* eap1 = (__hip_bfloat16*)alloc((size_t)NE * 16 * 2);
    __hip_bfloat16* eap  = (__hip_bfloat16*)alloc((size_t)NE * 16 * 2);
    __hip_bfloat16* q1b  = (__hip_bfloat16*)alloc((size_t)NN * 128 * 2);
    __hip_bfloat16* sk1b = (__hip_bfloat16*)alloc((size_t)NN * 128 * 2);
    __hip_bfloat16* hb   = (__hip_bfloat16*)alloc((size_t)NN * 128 * 2);
    __hip_bfloat16* kv1  = (__hip_bfloat16*)alloc((size_t)NN * 256 * 2);
    __hip_bfloat16* Wp1  = (__hip_bfloat16*)alloc((size_t)34 * 2048 * 2);
    __hip_bfloat16* Wp2  = (__hip_bfloat16*)alloc((size_t)17 * 2048 * 2);
    // layer-2 aliases (dead layer-1 buffers, stream-ordered)
    __hip_bfloat16* q2b  = q1b;
    __hip_bfloat16* sk2b = sk1b;
    __hip_bfloat16* kv2  = kv1;

    // 1. prep: bucket histogram + weight packing (no global atomics)
    prep<<<PB_PA2, 256, 0, stream>>>(dstp, blkcnt,
        Wq1, Wk1, Wv1, Ws1, bq1, bk1, bv1, bs1, We1,
        Wq2, Wk2, Wv2, Ws2, bq2, bk2, bv2, bs2, We2,
        Wp1, bcat1, Wp2, bcat2);

    // 2. passC: LDS-staged bucket sort carrying sidx + bf16 ea (burst writes)
    passC<<<NCB, 1024, 0, stream>>>(dstp, srcp, eattr, blkcnt, sidx, eap1, bstart);

    // 3. passD ∥ layer-1 GEMM: node sort + eap permute (hidden under gemm1)
    passD_mid<<<DB_ALL, 1024, 0, stream>>>(sidx, eap1, bstart, off, srcs, eap,
                                           x, Wp1, bcat1, q1b, kv1, sk1b, wq1);

    // 4. layer 1 aggregation
    agg_l1<<<NN / 4, 256, 0, stream>>>(off, srcs, eap, We1, wq1, q1b, kv1, sk1b, hb);

    // 5. layer 2 GEMM
    gemm_fused<64, 16, false><<<NN / 16, 256, 0, stream>>>(
        hb, Wp2, bcat2, q2b, kv2, sk2b, wq2);

    // 6. layer 2 aggregation
    agg_l2<<<NN / 4, 256, 0, stream>>>(off, srcs, eap, We2, wq2, q2b, kv2, sk2b, (float*)d_out);
}